// Round 3
// baseline (207.344 us; speedup 1.0000x reference)
//
#include <hip/hip_runtime.h>
#include <hip/hip_bf16.h>

// MyConv1d_ell_2_sequential: B=16384, C=128, O=128, LIN=18, out (B,128,54) fp32.
// out[b,o,t*6+l] = sum over tap instances (j, i, coef) of coef * sum_c x[b,c,i]*Fj[c,o]
// Fj = 5 tap planes (f2 k=0,1 scaled 1/sqrt(256); f3 k=0..2 scaled 1/sqrt(384)).
// R2: LDS-transpose epilogue -> coalesced float4 stores (286 -> 188 us).
// R3: kill address-divergent loads: (a) filters pre-packed to MFMA B-fragments in
//     d_ws by a pre-kernel (160 divergent scalar loads/thread -> 20 coalesced
//     dwordx4), (b) x staging reads made block-contiguous float2 + LDS scatter.

using short8 = short __attribute__((ext_vector_type(8)));
using f32x4  = float __attribute__((ext_vector_type(4)));

#define DEVINL __device__ __forceinline__

DEVINL unsigned short f2bf(float f) {
    unsigned int u = __float_as_uint(f);
    unsigned int r = u + 0x7FFFu + ((u >> 16) & 1u);   // RNE
    return (unsigned short)(r >> 16);
}

// instance tables: per i (0..14), list of (acc slot, filter plane j)
__constant__ constexpr int START[16] = {0,6,12,18,23,31,37,46,54,63,69,77,82,88,94,100};
__constant__ constexpr int SLOT[100] = {
 0,1,2,3,3,4,
 1,2,3,4,4,5,
 6,7,8,9,9,10,
 7,8,9,10,10,
 0,11,12,13,2,14,14,3,
 12,1,13,14,3,4,
 15,6,16,1,17,8,9,3,4,
 16,7,17,2,9,10,4,5,
 18,11,19,7,13,2,14,9,10,
 19,12,8,14,3,10,
 20,15,12,17,8,14,3,3,
 16,13,9,4,4,
 18,16,13,9,9,4,
 19,17,14,10,10,5,
 20,19,17,14,14,10
};
__constant__ constexpr int JJ[100] = {
 0,0,2,2,2,2,
 0,0,2,2,2,2,
 0,0,2,2,2,2,
 0,0,2,2,2,
 1,0,0,2,3,2,2,3,
 0,1,0,2,3,3,
 0,1,0,1,2,3,3,3,3,
 0,1,0,1,3,3,3,3,
 0,1,0,1,3,4,3,3,3,
 0,1,1,3,4,3,
 0,1,1,3,4,3,4,4,
 1,1,4,4,4,
 1,1,4,4,4,4,
 1,1,4,4,4,4,
 1,1,4,4,4,4
};
// slot -> u (column in 0..53); remaining 33 columns are structural zeros
__constant__ constexpr int UCOL[21] = {0,1,2,3,4,5,6,7,8,9,10,12,13,14,15,18,19,20,24,25,30};

// ---- pre-kernel: pack filters into MFMA B-fragments (bf16, pre-scaled) ----
// bp layout: [wid(8)][j(5)][q(4)][lane(64)] x short8  (160 KB total)
// B-frag lane L holds Fj[c = q*32 + (L>>4)*8 + e][o = wid*16 + (L&15)]
__global__ __launch_bounds__(256)
void pack_filters(const float* __restrict__ f2, const float* __restrict__ f3,
                  unsigned short* __restrict__ bp)
{
    int p = blockIdx.x * 256 + threadIdx.x;       // 0..10239
    if (p >= 10240) return;
    int L   = p & 63;
    int t   = p >> 6;                             // wid*20 + j*4 + q
    int q   = t & 3;
    int j   = (t >> 2) % 5;
    int wid = t / 20;
    int o   = wid * 16 + (L & 15);
    int c0  = q * 32 + (L >> 4) * 8;
    float scale = (j < 2) ? 0.0625f : 0.051031036307982884f;
    unsigned short v[8];
    #pragma unroll
    for (int e = 0; e < 8; ++e) {
        int c = c0 + e;
        float f = (j < 2) ? f2[(o * 128 + c) * 2 + j]
                          : f3[(o * 128 + c) * 3 + (j - 2)];
        v[e] = f2bf(f * scale);
    }
    *reinterpret_cast<short8*>(bp + (long)p * 8) = *reinterpret_cast<const short8*>(v);
}

__global__ __launch_bounds__(512, 2)
void conv1d_ell_kernel(const float* __restrict__ x,
                       const unsigned short* __restrict__ bpack,
                       float* __restrict__ out)
{
    // Phase 1: x tile, bf16, layout [i(15)][b(16)][c(128)], XOR-swizzled.  61440 B
    // Phase 2 (epilogue): float buffer [rr(2)][o(128)][u(54)].              55296 B
    __shared__ __align__(16) unsigned char smem[61440];
    unsigned short* xl = reinterpret_cast<unsigned short*>(smem);
    float*          ob = reinterpret_cast<float*>(smem);

    const int tid  = threadIdx.x;
    const int lane = tid & 63;
    const int wid  = tid >> 6;          // 0..7  -> o tile = wid*16
    const int m    = lane & 15;         // A row / D col component
    const int kblk = lane >> 4;         // 0..3
    const int g    = lane >> 4;         // D row group

    const long b_base = (long)blockIdx.x * 16;

    // ---- stage x -> LDS: block-contiguous float2 reads, transpose-scatter ----
    // flat float2 index f over the block's 16 rows: f = b*1152 + c*9 + lp,
    // covering floats (c*18 + 2*lp, +1) of row b.  Fully coalesced reads.
    {
        const float2* xp = reinterpret_cast<const float2*>(x + b_base * 2304);
        #pragma unroll
        for (int r = 0; r < 36; ++r) {
            int f   = r * 512 + tid;        // 0..18431
            int b   = f / 1152;
            int rem = f - b * 1152;
            int c   = rem / 9;
            int lp  = rem - c * 9;
            float2 w = xp[f];
            int l0 = lp * 2;
            if (l0 < 15)
                xl[(l0 * 2048 + b * 128 + c) ^ ((b & 7) << 3)] = f2bf(w.x);
            if (l0 + 1 < 15)
                xl[((l0 + 1) * 2048 + b * 128 + c) ^ ((b & 7) << 3)] = f2bf(w.y);
        }
    }

    // ---- load pre-packed filter B-fragments: 20 coalesced 16B loads ----
    short8 bfrag[5][4];
    {
        const unsigned short* bp = bpack + ((long)(wid * 20) * 64 + lane) * 8;
        #pragma unroll
        for (int j = 0; j < 5; ++j)
            #pragma unroll
            for (int q = 0; q < 4; ++q)
                bfrag[j][q] = *reinterpret_cast<const short8*>(bp + (long)(j * 4 + q) * 64 * 8);
    }

    f32x4 acc[21];
    #pragma unroll
    for (int s = 0; s < 21; ++s) acc[s] = (f32x4){0.f, 0.f, 0.f, 0.f};

    __syncthreads();

    // ---- main loop: for each position i, 4 A-frags (k-chunks), then instances ----
    #pragma unroll
    for (int i = 0; i < 15; ++i) {
        short8 a[4];
        #pragma unroll
        for (int q = 0; q < 4; ++q) {
            int c0 = q * 32 + kblk * 8;
            int idx = (i * 2048 + m * 128 + c0) ^ ((m & 7) << 3);
            a[q] = *reinterpret_cast<const short8*>(&xl[idx]);
        }
        #pragma unroll
        for (int n = START[i]; n < START[i + 1]; ++n) {
            const int s = SLOT[n];
            const int j = JJ[n];
            #pragma unroll
            for (int q = 0; q < 4; ++q) {
                acc[s] = __builtin_amdgcn_mfma_f32_16x16x32_bf16(a[q], bfrag[j][q], acc[s], 0, 0, 0);
            }
        }
    }

    // ---- epilogue: LDS transpose -> coalesced float4 stores ----
    // D layout: lane holds (o = oc, b_local = g*4 + r) for r=0..3 in acc[.][r].
    // Chunk k (0..7) covers block-local rows {2k, 2k+1}; owning lanes g == k>>1.
    const int oc = wid * 16 + m;
    __syncthreads();                    // all a-frag LDS reads done; safe to reuse

    // zero-fill once: structural-zero columns persist across chunks
    for (int v = tid; v < 3456; v += 512)
        *reinterpret_cast<float4*>(ob + 4 * v) = make_float4(0.f, 0.f, 0.f, 0.f);
    __syncthreads();

    #pragma unroll
    for (int k = 0; k < 8; ++k) {
        if (g == (k >> 1)) {
            #pragma unroll
            for (int rr = 0; rr < 2; ++rr) {
                const int r = 2 * (k & 1) + rr;          // acc register index
                float* dst = ob + (rr * 128 + oc) * 54;  // bank stride 54: conflict-free
                #pragma unroll
                for (int s = 0; s < 21; ++s) dst[UCOL[s]] = acc[s][r];
            }
        }
        __syncthreads();
        // 2 adjacent b-rows = one contiguous 55296-B global region
        float* obase = out + (b_base + 2 * k) * 6912;
        for (int v = tid; v < 3456; v += 512) {
            float4 w = *reinterpret_cast<const float4*>(ob + 4 * v);
            *reinterpret_cast<float4*>(obase + 4 * v) = w;
        }
        if (k < 7) __syncthreads();
    }
}

extern "C" void kernel_launch(void* const* d_in, const int* in_sizes, int n_in,
                              void* d_out, int out_size, void* d_ws, size_t ws_size,
                              hipStream_t stream) {
    const float* x   = (const float*)d_in[0];
    const float* sos = (const float*)d_in[1];
    const float* f2  = (const float*)d_in[2];
    const float* f3  = (const float*)d_in[3];
    float* out = (float*)d_out;
    unsigned short* bp = (unsigned short*)d_ws;    // 160 KB of fragments

    pack_filters<<<dim3(40), dim3(256), 0, stream>>>(f2, f3, bp);
    conv1d_ell_kernel<<<dim3(1024), dim3(512), 0, stream>>>(x, bp, out);

    // output 1: pass-through copy of sum_of_squares (16384 floats)
    hipMemcpyAsync(out + 113246208LL, sos, 16384 * sizeof(float),
                   hipMemcpyDeviceToDevice, stream);
}

// Round 5
// 145.376 us; speedup vs baseline: 1.4263x; 1.4263x over previous
//
#include <hip/hip_runtime.h>
#include <hip/hip_bf16.h>

// MyConv1d_ell_2_sequential: B=16384, C=128, O=128, LIN=18, out (B,128,54) fp32.
// out[b,o,t*6+l] = sum over tap instances (j, i, coef) of coef * sum_c x[b,c,i]*Fj[c,o]
// Fj = 5 tap planes (f2 k=0,1 scaled 1/sqrt(256); f3 k=0..2 scaled 1/sqrt(384)).
// R2: LDS-transpose epilogue -> coalesced float4 stores (286 -> 188 us).
// R3: bundled staging rewrite (16-way LDS write conflicts, REGRESSED) + filter
//     pre-pack (good). 207 us.
// R4: R2 verbatim + ONLY the filter pre-pack (20 coalesced dwordx4 per thread
//     replaces 160 divergent scalar loads = ~10K TA line-transactions/wave).
// R5: resubmit of R4 (container died before benching).

using short8 = short __attribute__((ext_vector_type(8)));
using f32x4  = float __attribute__((ext_vector_type(4)));

#define DEVINL __device__ __forceinline__

DEVINL unsigned short f2bf(float f) {
    unsigned int u = __float_as_uint(f);
    unsigned int r = u + 0x7FFFu + ((u >> 16) & 1u);   // RNE
    return (unsigned short)(r >> 16);
}

// instance tables: per i (0..14), list of (acc slot, filter plane j)
__constant__ constexpr int START[16] = {0,6,12,18,23,31,37,46,54,63,69,77,82,88,94,100};
__constant__ constexpr int SLOT[100] = {
 0,1,2,3,3,4,
 1,2,3,4,4,5,
 6,7,8,9,9,10,
 7,8,9,10,10,
 0,11,12,13,2,14,14,3,
 12,1,13,14,3,4,
 15,6,16,1,17,8,9,3,4,
 16,7,17,2,9,10,4,5,
 18,11,19,7,13,2,14,9,10,
 19,12,8,14,3,10,
 20,15,12,17,8,14,3,3,
 16,13,9,4,4,
 18,16,13,9,9,4,
 19,17,14,10,10,5,
 20,19,17,14,14,10
};
__constant__ constexpr int JJ[100] = {
 0,0,2,2,2,2,
 0,0,2,2,2,2,
 0,0,2,2,2,2,
 0,0,2,2,2,
 1,0,0,2,3,2,2,3,
 0,1,0,2,3,3,
 0,1,0,1,2,3,3,3,3,
 0,1,0,1,3,3,3,3,
 0,1,0,1,3,4,3,3,3,
 0,1,1,3,4,3,
 0,1,1,3,4,3,4,4,
 1,1,4,4,4,
 1,1,4,4,4,4,
 1,1,4,4,4,4,
 1,1,4,4,4,4
};
// slot -> u (column in 0..53); remaining 33 columns are structural zeros
__constant__ constexpr int UCOL[21] = {0,1,2,3,4,5,6,7,8,9,10,12,13,14,15,18,19,20,24,25,30};

// ---- pre-kernel: pack filters into MFMA B-fragments (bf16, pre-scaled) ----
// bp layout: [wid(8)][j(5)][q(4)][lane(64)] x short8  (160 KB total)
// B-frag lane L holds Fj[c = q*32 + (L>>4)*8 + e][o = wid*16 + (L&15)]
__global__ __launch_bounds__(256)
void pack_filters(const float* __restrict__ f2, const float* __restrict__ f3,
                  unsigned short* __restrict__ bp)
{
    int p = blockIdx.x * 256 + threadIdx.x;       // 0..10239
    if (p >= 10240) return;
    int L   = p & 63;
    int t   = p >> 6;                             // wid*20 + j*4 + q
    int q   = t & 3;
    int j   = (t >> 2) % 5;
    int wid = t / 20;
    int o   = wid * 16 + (L & 15);
    int c0  = q * 32 + (L >> 4) * 8;
    float scale = (j < 2) ? 0.0625f : 0.051031036307982884f;
    unsigned short v[8];
    #pragma unroll
    for (int e = 0; e < 8; ++e) {
        int c = c0 + e;
        float f = (j < 2) ? f2[(o * 128 + c) * 2 + j]
                          : f3[(o * 128 + c) * 3 + (j - 2)];
        v[e] = f2bf(f * scale);
    }
    *reinterpret_cast<short8*>(bp + (long)p * 8) = *reinterpret_cast<const short8*>(v);
}

__global__ __launch_bounds__(512, 2)
void conv1d_ell_kernel(const float* __restrict__ x,
                       const unsigned short* __restrict__ bpack,
                       float* __restrict__ out)
{
    // Phase 1: x tile, bf16, layout [i(15)][b(16)][c(128)], XOR-swizzled.  61440 B
    // Phase 2 (epilogue): float buffer [rr(2)][o(128)][u(54)].              55296 B
    __shared__ __align__(16) unsigned char smem[61440];
    unsigned short* xl = reinterpret_cast<unsigned short*>(smem);
    float*          ob = reinterpret_cast<float*>(smem);

    const int tid  = threadIdx.x;
    const int lane = tid & 63;
    const int wid  = tid >> 6;          // 0..7  -> o tile = wid*16
    const int m    = lane & 15;         // A row / D col component
    const int kblk = lane >> 4;         // 0..3
    const int g    = lane >> 4;         // D row group

    const long b_base = (long)blockIdx.x * 16;

    // ---- stage x -> LDS (fp32 -> bf16, transpose (b,c,i)->(i,b,c)) ----
    // (R2 pattern: conflict-free LDS writes; divergent-but-moderate reads)
    #pragma unroll
    for (int q = 0; q < 4; ++q) {
        int r = tid + q * 512;          // 0..2047
        int b = r >> 7;                 // 0..15
        int c = r & 127;
        const float* px = x + (b_base + b) * 2304 + (long)c * 18;
        float v[16];
        #pragma unroll
        for (int t = 0; t < 8; ++t) {
            float2 w = reinterpret_cast<const float2*>(px)[t];
            v[2*t] = w.x; v[2*t+1] = w.y;
        }
        #pragma unroll
        for (int i = 0; i < 15; ++i) {
            int idx = (i * 2048 + b * 128 + c) ^ ((b & 7) << 3);
            xl[idx] = f2bf(v[i]);
        }
    }

    // ---- load pre-packed filter B-fragments: 20 coalesced 16B loads ----
    short8 bfrag[5][4];
    {
        const unsigned short* bp = bpack + ((long)(wid * 20) * 64 + lane) * 8;
        #pragma unroll
        for (int j = 0; j < 5; ++j)
            #pragma unroll
            for (int q = 0; q < 4; ++q)
                bfrag[j][q] = *reinterpret_cast<const short8*>(bp + (long)(j * 4 + q) * 64 * 8);
    }

    f32x4 acc[21];
    #pragma unroll
    for (int s = 0; s < 21; ++s) acc[s] = (f32x4){0.f, 0.f, 0.f, 0.f};

    __syncthreads();

    // ---- main loop: for each position i, 4 A-frags (k-chunks), then instances ----
    #pragma unroll
    for (int i = 0; i < 15; ++i) {
        short8 a[4];
        #pragma unroll
        for (int q = 0; q < 4; ++q) {
            int c0 = q * 32 + kblk * 8;
            int idx = (i * 2048 + m * 128 + c0) ^ ((m & 7) << 3);
            a[q] = *reinterpret_cast<const short8*>(&xl[idx]);
        }
        #pragma unroll
        for (int n = START[i]; n < START[i + 1]; ++n) {
            const int s = SLOT[n];
            const int j = JJ[n];
            #pragma unroll
            for (int q = 0; q < 4; ++q) {
                acc[s] = __builtin_amdgcn_mfma_f32_16x16x32_bf16(a[q], bfrag[j][q], acc[s], 0, 0, 0);
            }
        }
    }

    // ---- epilogue: LDS transpose -> coalesced float4 stores ----
    // D layout: lane holds (o = oc, b_local = g*4 + r) for r=0..3 in acc[.][r].
    // Chunk k (0..7) covers block-local rows {2k, 2k+1}; owning lanes g == k>>1.
    const int oc = wid * 16 + m;
    __syncthreads();                    // all a-frag LDS reads done; safe to reuse

    // zero-fill once: structural-zero columns persist across chunks
    for (int v = tid; v < 3456; v += 512)
        *reinterpret_cast<float4*>(ob + 4 * v) = make_float4(0.f, 0.f, 0.f, 0.f);
    __syncthreads();

    #pragma unroll
    for (int k = 0; k < 8; ++k) {
        if (g == (k >> 1)) {
            #pragma unroll
            for (int rr = 0; rr < 2; ++rr) {
                const int r = 2 * (k & 1) + rr;          // acc register index
                float* dst = ob + (rr * 128 + oc) * 54;  // bank stride 54: conflict-free
                #pragma unroll
                for (int s = 0; s < 21; ++s) dst[UCOL[s]] = acc[s][r];
            }
        }
        __syncthreads();
        // 2 adjacent b-rows = one contiguous 55296-B global region
        float* obase = out + (b_base + 2 * k) * 6912;
        for (int v = tid; v < 3456; v += 512) {
            float4 w = *reinterpret_cast<const float4*>(ob + 4 * v);
            *reinterpret_cast<float4*>(obase + 4 * v) = w;
        }
        if (k < 7) __syncthreads();
    }
}

extern "C" void kernel_launch(void* const* d_in, const int* in_sizes, int n_in,
                              void* d_out, int out_size, void* d_ws, size_t ws_size,
                              hipStream_t stream) {
    const float* x   = (const float*)d_in[0];
    const float* sos = (const float*)d_in[1];
    const float* f2  = (const float*)d_in[2];
    const float* f3  = (const float*)d_in[3];
    float* out = (float*)d_out;
    unsigned short* bp = (unsigned short*)d_ws;    // 160 KB of fragments

    pack_filters<<<dim3(40), dim3(256), 0, stream>>>(f2, f3, bp);
    conv1d_ell_kernel<<<dim3(1024), dim3(512), 0, stream>>>(x, bp, out);

    // output 1: pass-through copy of sum_of_squares (16384 floats)
    hipMemcpyAsync(out + 113246208LL, sos, 16384 * sizeof(float),
                   hipMemcpyDeviceToDevice, stream);
}